// Round 1
// baseline (300.138 us; speedup 1.0000x reference)
//
#include <hip/hip_runtime.h>
#include <stdint.h>

#define S_LEN 2048
#define DIM   64
#define QBLK  128
#define KVBLK 32
#define KLD   72   // K-tile LDS row stride (bf16 elems): 32x64 tile, pad to kill conflicts
#define VLD   40   // V^T-tile LDS row stride (keys + pad)
#define PLD   40   // P-tile LDS row stride (keys + pad)

typedef __attribute__((ext_vector_type(8))) short short8;
typedef __attribute__((ext_vector_type(4))) float f32x4;

// fp32 -> bf16 round-to-nearest-even (inputs are finite; no NaN path needed)
static __device__ __forceinline__ unsigned short f2bf(float f) {
    union { float f; uint32_t u; } cv; cv.f = f;
    uint32_t u = cv.u;
    return (unsigned short)((u + 0x7fffu + ((u >> 16) & 1u)) >> 16);
}

__global__ __launch_bounds__(256, 2)
void attn_fwd(const float* __restrict__ qp, const float* __restrict__ kp,
              const float* __restrict__ vp, float* __restrict__ op) {
    const int bh   = blockIdx.x >> 4;   // 64 (b,h) pairs
    const int qb   = blockIdx.x & 15;   // 16 Q-tiles of 128 rows
    const int tid  = threadIdx.x;
    const int wave = tid >> 6;
    const int lane = tid & 63;
    const int g    = lane >> 4;         // 16-lane group 0..3
    const int r    = lane & 15;

    const size_t base = (size_t)bh * (S_LEN * DIM);
    const float* qg = qp + base;
    const float* kg = kp + base;
    const float* vg = vp + base;
    float*       og = op + base;

    __shared__ unsigned short klds[KVBLK * KLD];     // K tile, row-major [key][d]
    __shared__ unsigned short vtlds[DIM * VLD];      // V tile, transposed [d][key]
    __shared__ unsigned short plds[4][32 * PLD];     // per-wave P tile [qrow][key]

    // ---- Q fragments in registers, pre-scaled by 1/sqrt(64)=0.125 (exact) ----
    // A-frag layout: row = lane&15, k = 8*(lane>>4)+i (contiguous bf16x8)
    const int q0 = qb * QBLK + wave * 32;
    short8 qfrag[2][2];
#pragma unroll
    for (int mt = 0; mt < 2; ++mt) {
        const float* qrow = qg + (size_t)(q0 + mt * 16 + r) * DIM;
#pragma unroll
        for (int ks = 0; ks < 2; ++ks) {
            const f32x4 a = *reinterpret_cast<const f32x4*>(qrow + ks * 32 + 8 * g);
            const f32x4 b = *reinterpret_cast<const f32x4*>(qrow + ks * 32 + 8 * g + 4);
            short8 t;
            t[0] = (short)f2bf(a[0] * 0.125f);
            t[1] = (short)f2bf(a[1] * 0.125f);
            t[2] = (short)f2bf(a[2] * 0.125f);
            t[3] = (short)f2bf(a[3] * 0.125f);
            t[4] = (short)f2bf(b[0] * 0.125f);
            t[5] = (short)f2bf(b[1] * 0.125f);
            t[6] = (short)f2bf(b[2] * 0.125f);
            t[7] = (short)f2bf(b[3] * 0.125f);
            qfrag[mt][ks] = t;
        }
    }

    // ---- flash state: O accumulators + running (m, l) per row ----
    f32x4 o[2][4];
    float m_run[2][4], l_run[2][4];
#pragma unroll
    for (int mt = 0; mt < 2; ++mt) {
#pragma unroll
        for (int nt = 0; nt < 4; ++nt) { f32x4 z = {0.f, 0.f, 0.f, 0.f}; o[mt][nt] = z; }
#pragma unroll
        for (int rg = 0; rg < 4; ++rg) { m_run[mt][rg] = -INFINITY; l_run[mt][rg] = 0.0f; }
    }

    // staging assignments
    const int krow = tid >> 3;          // K: 32 rows x 8 col-groups
    const int kc0  = (tid & 7) * 8;
    const int vd   = tid & 63;          // V^T: d-major (coalesced global reads)
    const int vk0  = (tid >> 6) * 8;

    for (int kv0 = 0; kv0 < S_LEN; kv0 += KVBLK) {
        __syncthreads();    // previous iteration's LDS reads done before overwrite
        {   // ---- stage K tile (coalesced float4 reads, one b128 LDS write) ----
            const float* src = kg + (size_t)(kv0 + krow) * DIM + kc0;
            const f32x4 a = *reinterpret_cast<const f32x4*>(src);
            const f32x4 b = *reinterpret_cast<const f32x4*>(src + 4);
            short8 t;
            t[0] = (short)f2bf(a[0]); t[1] = (short)f2bf(a[1]);
            t[2] = (short)f2bf(a[2]); t[3] = (short)f2bf(a[3]);
            t[4] = (short)f2bf(b[0]); t[5] = (short)f2bf(b[1]);
            t[6] = (short)f2bf(b[2]); t[7] = (short)f2bf(b[3]);
            *reinterpret_cast<short8*>(&klds[krow * KLD + kc0]) = t;
        }
        {   // ---- stage V^T tile: lane sweeps d (contiguous 256B global reads),
            //      writes 8 keys of one d-row as a single b128 ----
            const float* src = vg + (size_t)(kv0 + vk0) * DIM + vd;
            short8 t;
#pragma unroll
            for (int i = 0; i < 8; ++i) t[i] = (short)f2bf(src[(size_t)i * DIM]);
            *reinterpret_cast<short8*>(&vtlds[vd * VLD + vk0]) = t;
        }
        __syncthreads();

        // ---- S = (Q/8) K^T : D[q][key], C/D layout col=lane&15(key), row=4g+reg(q) ----
        f32x4 s[2][2];
#pragma unroll
        for (int mt = 0; mt < 2; ++mt) {
#pragma unroll
            for (int nt = 0; nt < 2; ++nt) {
                f32x4 acc = {0.f, 0.f, 0.f, 0.f};
#pragma unroll
                for (int ks = 0; ks < 2; ++ks) {
                    const short8 kf = *reinterpret_cast<const short8*>(
                        &klds[(nt * 16 + r) * KLD + ks * 32 + 8 * g]);
                    acc = __builtin_amdgcn_mfma_f32_16x16x32_bf16(qfrag[mt][ks], kf, acc, 0, 0, 0);
                }
                s[mt][nt] = acc;
            }
        }

        // ---- online softmax (row stats live in lanes sharing g; reduce over 16 lanes) ----
#pragma unroll
        for (int mt = 0; mt < 2; ++mt) {
            float mx[4], al[4], ls[4];
#pragma unroll
            for (int rg = 0; rg < 4; ++rg) mx[rg] = fmaxf(s[mt][0][rg], s[mt][1][rg]);
#pragma unroll
            for (int rg = 0; rg < 4; ++rg) {
#pragma unroll
                for (int msk = 1; msk <= 8; msk <<= 1)
                    mx[rg] = fmaxf(mx[rg], __shfl_xor(mx[rg], msk));
            }
#pragma unroll
            for (int rg = 0; rg < 4; ++rg) {
                const float mnew = fmaxf(m_run[mt][rg], mx[rg]);
                al[rg] = __expf(m_run[mt][rg] - mnew);   // exp(-inf)=0 on first tile
                m_run[mt][rg] = mnew;
                const float p0 = __expf(s[mt][0][rg] - mnew);
                const float p1 = __expf(s[mt][1][rg] - mnew);
                ls[rg] = p0 + p1;
                const int prow = (mt * 16 + 4 * g + rg) * PLD;
                plds[wave][prow + r]      = f2bf(p0);
                plds[wave][prow + 16 + r] = f2bf(p1);
            }
#pragma unroll
            for (int rg = 0; rg < 4; ++rg) {
#pragma unroll
                for (int msk = 1; msk <= 8; msk <<= 1)
                    ls[rg] += __shfl_xor(ls[rg], msk);
                l_run[mt][rg] = l_run[mt][rg] * al[rg] + ls[rg];
            }
#pragma unroll
            for (int nt = 0; nt < 4; ++nt) {
                f32x4 t = o[mt][nt];
                t[0] *= al[0]; t[1] *= al[1]; t[2] *= al[2]; t[3] *= al[3];
                o[mt][nt] = t;
            }
        }
        __syncthreads();    // conservative: order P writes (cross-lane) before b128 reads

        // ---- O += P V : A-frag from plds (row=r, keys contiguous), B-frag from vtlds ----
        short8 vtf[4];
#pragma unroll
        for (int nt = 0; nt < 4; ++nt)
            vtf[nt] = *reinterpret_cast<const short8*>(&vtlds[(nt * 16 + r) * VLD + 8 * g]);
#pragma unroll
        for (int mt = 0; mt < 2; ++mt) {
            const short8 pf = *reinterpret_cast<const short8*>(
                &plds[wave][(mt * 16 + r) * PLD + 8 * g]);
#pragma unroll
            for (int nt = 0; nt < 4; ++nt)
                o[mt][nt] = __builtin_amdgcn_mfma_f32_16x16x32_bf16(pf, vtf[nt], o[mt][nt], 0, 0, 0);
        }
    }

    // ---- epilogue: O / l, fp32 stores ----
#pragma unroll
    for (int mt = 0; mt < 2; ++mt) {
#pragma unroll
        for (int rg = 0; rg < 4; ++rg) {
            const float inv = 1.0f / l_run[mt][rg];
            float* dst = og + (size_t)(q0 + mt * 16 + 4 * g + rg) * DIM + r;
#pragma unroll
            for (int nt = 0; nt < 4; ++nt)
                dst[nt * 16] = o[mt][nt][rg] * inv;
        }
    }
}

extern "C" void kernel_launch(void* const* d_in, const int* in_sizes, int n_in,
                              void* d_out, int out_size, void* d_ws, size_t ws_size,
                              hipStream_t stream) {
    const float* q = (const float*)d_in[0];
    const float* k = (const float*)d_in[1];
    const float* v = (const float*)d_in[2];
    float* out = (float*)d_out;
    const int nbh = in_sizes[0] / (S_LEN * DIM);      // B*H = 64
    dim3 grid(nbh * (S_LEN / QBLK));                  // 1024 blocks
    attn_fwd<<<grid, 256, 0, stream>>>(q, k, v, out);
}

// Round 2
// 205.074 us; speedup vs baseline: 1.4636x; 1.4636x over previous
//
#include <hip/hip_runtime.h>
#include <stdint.h>

#define S_LEN 2048
#define DIM   64
#define QBLK  128
#define KVBLK 64
#define NKV   (S_LEN / KVBLK)   // 32
#define PLD   72                // P LDS row stride (u16): b64 writes & b128 reads bank-optimal

typedef __attribute__((ext_vector_type(8))) short short8;
typedef __attribute__((ext_vector_type(4))) float f32x4;

// fp32 -> bf16 round-to-nearest-even (cold paths only)
static __device__ __forceinline__ unsigned short f2bf(float f) {
    union { float f; uint32_t u; } cv; cv.f = f;
    uint32_t u = cv.u;
    return (unsigned short)((u + 0x7fffu + ((u >> 16) & 1u)) >> 16);
}

// async global->LDS, 16B per lane, LDS dest = wave-uniform base + lane*16
static __device__ __forceinline__ void gload16(const void* g, void* l) {
    __builtin_amdgcn_global_load_lds(
        (const __attribute__((address_space(1))) unsigned int*)g,
        (__attribute__((address_space(3))) unsigned int*)l, 16, 0, 0);
}

// ---------------- pre-kernel 1: K fp32 -> bf16, per-row 16B-chunk XOR swizzle ----------------
// kws[bh][s][ (c ^ (s&7))*8 + j ] = bf16( K[bh][s][ c*8 + j ] )
__global__ void cvt_k(const float* __restrict__ kp, unsigned short* __restrict__ kws) {
    const int idx = blockIdx.x * 256 + threadIdx.x;   // one 8-elem chunk per thread
    const int c   = idx & 7;
    const int s   = (idx >> 3) & (S_LEN - 1);
    const int bh  = idx >> 14;                        // 2048*8 chunks per bh
    const float* src = kp + ((size_t)bh * S_LEN + s) * DIM + c * 8;
    const f32x4 a = *reinterpret_cast<const f32x4*>(src);
    const f32x4 b = *reinterpret_cast<const f32x4*>(src + 4);
    short8 t;
    t[0] = (short)f2bf(a[0]); t[1] = (short)f2bf(a[1]);
    t[2] = (short)f2bf(a[2]); t[3] = (short)f2bf(a[3]);
    t[4] = (short)f2bf(b[0]); t[5] = (short)f2bf(b[1]);
    t[6] = (short)f2bf(b[2]); t[7] = (short)f2bf(b[3]);
    unsigned short* dst = kws + ((size_t)bh * S_LEN + s) * DIM + (size_t)((c ^ (s & 7)) * 8);
    *reinterpret_cast<short8*>(dst) = t;
}

// ---------------- pre-kernel 2: V fp32 -> bf16 transposed [d][key], chunk-swizzled + pi-interleaved ----
// storage slot (d, tile t, chunk c_st, j): logical pos p = (c_st^(d&7))*8+j, key = t*64 + (p&3)*16 + (p>>2)
__global__ void cvt_v(const float* __restrict__ vp, unsigned short* __restrict__ vtws) {
    const int bh = blockIdx.x >> 5;
    const int t  = blockIdx.x & 31;
    const int tid = threadIdx.x;
    __shared__ unsigned short ldsT[DIM][72];          // [d][local key]

    const int i = tid >> 2;                           // local key 0..63
    const int dbase = (tid & 3) * 16;
    const float* src = vp + ((size_t)bh * S_LEN + t * 64 + i) * DIM + dbase;
#pragma unroll
    for (int q4 = 0; q4 < 4; ++q4) {
        const f32x4 a = *reinterpret_cast<const f32x4*>(src + q4 * 4);
#pragma unroll
        for (int j = 0; j < 4; ++j) ldsT[dbase + q4 * 4 + j][i] = f2bf(a[j]);
    }
    __syncthreads();
#pragma unroll
    for (int hh = 0; hh < 2; ++hh) {
        const int slot = tid + hh * 256;              // 0..511 = (d, c_st)
        const int d = slot >> 3, c_st = slot & 7;
        const int cl = c_st ^ (d & 7);
        short8 t8;
#pragma unroll
        for (int j = 0; j < 8; ++j) {
            const int p = cl * 8 + j;
            const int klocal = ((p & 3) << 4) + (p >> 2);   // pi(p)
            t8[j] = (short)ldsT[d][klocal];
        }
        unsigned short* dst = vtws + ((size_t)bh * DIM + d) * S_LEN + t * 64 + c_st * 8;
        *reinterpret_cast<short8*>(dst) = t8;
    }
}

// ---------------- main attention kernel ----------------
__global__ __launch_bounds__(256, 3)
void attn_fwd(const float* __restrict__ qp, const unsigned short* __restrict__ kws,
              const unsigned short* __restrict__ vtws, float* __restrict__ op) {
    // XCD swizzle: 1024 blocks, 8 XCDs -> XCD x gets logical blocks [x*128, x*128+128) = bh 8x..8x+7
    const int lb = (blockIdx.x & 7) * 128 + (blockIdx.x >> 3);
    const int bh = lb >> 4;
    const int qb = lb & 15;
    const int tid  = threadIdx.x;
    const int wave = tid >> 6;
    const int lane = tid & 63;
    const int g = lane >> 4;
    const int r = lane & 15;

    __shared__ unsigned short klds[2][KVBLK * DIM];   // [key][slot] swizzled image (8KB x2)
    __shared__ unsigned short vlds[2][DIM * KVBLK];   // [d][pos-slot] swizzled image (8KB x2)
    __shared__ unsigned short plds[4][32 * PLD];      // per-wave P, [qrow][pos]

    const float*          qg    = qp   + (size_t)bh * (S_LEN * DIM);
    const unsigned short* kbase = kws  + (size_t)bh * (S_LEN * DIM);
    const unsigned short* vbase = vtws + (size_t)bh * (S_LEN * DIM);
    float*                og    = op   + (size_t)bh * (S_LEN * DIM);

    // ---- Q fragments, pre-scaled by 1/sqrt(64)=0.125: row=lane&15, k=8g+i ----
    const int q0 = qb * QBLK + wave * 32;
    short8 qfrag[2][2];
#pragma unroll
    for (int mt = 0; mt < 2; ++mt) {
        const float* qrow = qg + (size_t)(q0 + mt * 16 + r) * DIM;
#pragma unroll
        for (int ks = 0; ks < 2; ++ks) {
            const f32x4 a = *reinterpret_cast<const f32x4*>(qrow + ks * 32 + 8 * g);
            const f32x4 b = *reinterpret_cast<const f32x4*>(qrow + ks * 32 + 8 * g + 4);
            short8 t;
            t[0] = (short)f2bf(a[0] * 0.125f); t[1] = (short)f2bf(a[1] * 0.125f);
            t[2] = (short)f2bf(a[2] * 0.125f); t[3] = (short)f2bf(a[3] * 0.125f);
            t[4] = (short)f2bf(b[0] * 0.125f); t[5] = (short)f2bf(b[1] * 0.125f);
            t[6] = (short)f2bf(b[2] * 0.125f); t[7] = (short)f2bf(b[3] * 0.125f);
            qfrag[mt][ks] = t;
        }
    }

    f32x4 o[2][4];
    float m_run[2][4], l_run[2][4];
#pragma unroll
    for (int mt = 0; mt < 2; ++mt) {
#pragma unroll
        for (int nt = 0; nt < 4; ++nt) { f32x4 z = {0.f, 0.f, 0.f, 0.f}; o[mt][nt] = z; }
#pragma unroll
        for (int rg = 0; rg < 4; ++rg) { m_run[mt][rg] = -INFINITY; l_run[mt][rg] = 0.0f; }
    }

    const int srow = lane >> 3, schk = lane & 7;

    // stage tile t into buf: 4 global_load_lds per wave (K 2, V^T 2); ws layouts already swizzled
    auto stage = [&](int t, int buf) {
        const int kv0 = t * KVBLK;
#pragma unroll
        for (int h = 0; h < 2; ++h) {
            const int row = wave * 16 + h * 8;   // wave-uniform LDS base row
            gload16(kbase + (size_t)(kv0 + row + srow) * DIM + schk * 8,
                    &klds[buf][row * DIM]);
            gload16(vbase + (size_t)(row + srow) * S_LEN + kv0 + schk * 8,
                    &vlds[buf][row * DIM]);
        }
    };

    stage(0, 0);
    __syncthreads();
    int cur = 0;

    for (int t = 0; t < NKV; ++t) {
        if (t + 1 < NKV) stage(t + 1, cur ^ 1);   // prefetch next tile (drains at end barrier)

        // ---- S = (Q/8) K^T : s[mt][nt], col=key(r), row=4g+rg ----
        f32x4 s[2][4];
#pragma unroll
        for (int nt = 0; nt < 4; ++nt) {
#pragma unroll
            for (int mt = 0; mt < 2; ++mt) { f32x4 z = {0.f,0.f,0.f,0.f}; s[mt][nt] = z; }
#pragma unroll
            for (int ks = 0; ks < 2; ++ks) {
                const short8 kf = *reinterpret_cast<const short8*>(
                    &klds[cur][(nt * 16 + r) * DIM + (((ks << 2) | g) ^ (r & 7)) * 8]);
#pragma unroll
                for (int mt = 0; mt < 2; ++mt)
                    s[mt][nt] = __builtin_amdgcn_mfma_f32_16x16x32_bf16(qfrag[mt][ks], kf, s[mt][nt], 0, 0, 0);
            }
        }

        // ---- online softmax; P packed b64 into per-wave LDS (pos p = 4r+nt) ----
#pragma unroll
        for (int mt = 0; mt < 2; ++mt) {
            float mx[4], al[4], ls[4];
#pragma unroll
            for (int rg = 0; rg < 4; ++rg) {
                mx[rg] = fmaxf(fmaxf(s[mt][0][rg], s[mt][1][rg]),
                               fmaxf(s[mt][2][rg], s[mt][3][rg]));
#pragma unroll
                for (int msk = 1; msk <= 8; msk <<= 1)
                    mx[rg] = fmaxf(mx[rg], __shfl_xor(mx[rg], msk));
                const float mnew = fmaxf(m_run[mt][rg], mx[rg]);
                al[rg] = __expf(m_run[mt][rg] - mnew);
                m_run[mt][rg] = mnew;
                const float p0 = __expf(s[mt][0][rg] - mnew);
                const float p1 = __expf(s[mt][1][rg] - mnew);
                const float p2 = __expf(s[mt][2][rg] - mnew);
                const float p3 = __expf(s[mt][3][rg] - mnew);
                ls[rg] = (p0 + p1) + (p2 + p3);
                uint32_t lo, hi;
                asm("v_cvt_pk_bf16_f32 %0, %1, %2" : "=v"(lo) : "v"(p0), "v"(p1));
                asm("v_cvt_pk_bf16_f32 %0, %1, %2" : "=v"(hi) : "v"(p2), "v"(p3));
                uint2 pk; pk.x = lo; pk.y = hi;
                *reinterpret_cast<uint2*>(&plds[wave][(mt * 16 + 4 * g + rg) * PLD + 4 * r]) = pk;
            }
#pragma unroll
            for (int rg = 0; rg < 4; ++rg) {
#pragma unroll
                for (int msk = 1; msk <= 8; msk <<= 1)
                    ls[rg] += __shfl_xor(ls[rg], msk);
                l_run[mt][rg] = l_run[mt][rg] * al[rg] + ls[rg];
            }
#pragma unroll
            for (int nt = 0; nt < 4; ++nt) {
                f32x4 tt = o[mt][nt];
                tt[0] *= al[0]; tt[1] *= al[1]; tt[2] *= al[2]; tt[3] *= al[3];
                o[mt][nt] = tt;
            }
        }

        // ---- O += P V (per-wave plds: no barrier, lgkm deps only) ----
        short8 pf[2][2];
#pragma unroll
        for (int mt = 0; mt < 2; ++mt)
#pragma unroll
            for (int ks = 0; ks < 2; ++ks)
                pf[mt][ks] = *reinterpret_cast<const short8*>(
                    &plds[wave][(mt * 16 + r) * PLD + ks * 32 + 8 * g]);
#pragma unroll
        for (int nt = 0; nt < 4; ++nt) {
#pragma unroll
            for (int ks = 0; ks < 2; ++ks) {
                const short8 vf = *reinterpret_cast<const short8*>(
                    &vlds[cur][(nt * 16 + r) * DIM + (((ks << 2) | g) ^ (r & 7)) * 8]);
#pragma unroll
                for (int mt = 0; mt < 2; ++mt)
                    o[mt][nt] = __builtin_amdgcn_mfma_f32_16x16x32_bf16(pf[mt][ks], vf, o[mt][nt], 0, 0, 0);
            }
        }

        __syncthreads();   // staged tile t+1 complete; all reads of buf[cur] done
        cur ^= 1;
    }

    // ---- epilogue: O / l ----
#pragma unroll
    for (int mt = 0; mt < 2; ++mt) {
#pragma unroll
        for (int rg = 0; rg < 4; ++rg) {
            const float inv = 1.0f / l_run[mt][rg];
            float* dst = og + (size_t)(q0 + mt * 16 + 4 * g + rg) * DIM + r;
#pragma unroll
            for (int nt = 0; nt < 4; ++nt)
                dst[nt * 16] = o[mt][nt][rg] * inv;
        }
    }
}

extern "C" void kernel_launch(void* const* d_in, const int* in_sizes, int n_in,
                              void* d_out, int out_size, void* d_ws, size_t ws_size,
                              hipStream_t stream) {
    const float* q = (const float*)d_in[0];
    const float* k = (const float*)d_in[1];
    const float* v = (const float*)d_in[2];
    float* out = (float*)d_out;
    unsigned short* kws  = (unsigned short*)d_ws;                       // 16.8 MB
    unsigned short* vtws = kws + (size_t)64 * S_LEN * DIM;              // 16.8 MB
    cvt_k<<<dim3(64 * S_LEN * 8 / 256), 256, 0, stream>>>(k, kws);      // 4096 blocks
    cvt_v<<<dim3(64 * (S_LEN / 64)), 256, 0, stream>>>(v, vtws);        // 2048 blocks
    attn_fwd<<<dim3(1024), 256, 0, stream>>>(q, kws, vtws, out);
}

// Round 4
// 146.933 us; speedup vs baseline: 2.0427x; 1.3957x over previous
//
#include <hip/hip_runtime.h>
#include <stdint.h>
#include <math.h>

#define S_LEN 2048
#define DIM   64
#define QBLK  128
#define KVBLK 64
#define NKV   (S_LEN / KVBLK)   // 32

typedef __attribute__((ext_vector_type(8))) short short8;
typedef __attribute__((ext_vector_type(4))) float f32x4;

// fp32 -> bf16 round-to-nearest-even (cold paths only)
static __device__ __forceinline__ unsigned short f2bf(float f) {
    union { float f; uint32_t u; } cv; cv.f = f;
    uint32_t u = cv.u;
    return (unsigned short)((u + 0x7fffu + ((u >> 16) & 1u)) >> 16);
}

// async global->LDS, 16B per lane, LDS dest = wave-uniform base + lane*16
static __device__ __forceinline__ void gload16(const void* g, void* l) {
    __builtin_amdgcn_global_load_lds(
        (const __attribute__((address_space(1))) unsigned int*)g,
        (__attribute__((address_space(3))) unsigned int*)l, 16, 0, 0);
}

// ---------------- pre-kernel 1: K fp32 -> bf16, per-row 16B-chunk XOR swizzle ----------------
__global__ void cvt_k(const float* __restrict__ kp, unsigned short* __restrict__ kws) {
    const int idx = blockIdx.x * 256 + threadIdx.x;
    const int c   = idx & 7;
    const int s   = (idx >> 3) & (S_LEN - 1);
    const int bh  = idx >> 14;
    const float* src = kp + ((size_t)bh * S_LEN + s) * DIM + c * 8;
    const f32x4 a = *reinterpret_cast<const f32x4*>(src);
    const f32x4 b = *reinterpret_cast<const f32x4*>(src + 4);
    short8 t;
    t[0] = (short)f2bf(a[0]); t[1] = (short)f2bf(a[1]);
    t[2] = (short)f2bf(a[2]); t[3] = (short)f2bf(a[3]);
    t[4] = (short)f2bf(b[0]); t[5] = (short)f2bf(b[1]);
    t[6] = (short)f2bf(b[2]); t[7] = (short)f2bf(b[3]);
    unsigned short* dst = kws + ((size_t)bh * S_LEN + s) * DIM + (size_t)((c ^ (s & 7)) * 8);
    *reinterpret_cast<short8*>(dst) = t;
}

// ---------------- pre-kernel 2: V fp32 -> bf16 transposed [d][key-position], kappa-permuted ----
// Read position p (in 64-key tile) must hold key kappa(p) = 32*p5 + 8*p4 + 4*p3 + 16*p2 + 2*p1 + p0,
// so that mfma k-slot (ks, k=8g+i) at position 32ks+8g+i sees key 32ks+16(i>>2)+4g+(i&3) = phi(k),
// matching the lane-local P ownership (keys 16nt+4g+rg) of the swapped-QK^T softmax.
// Positions additionally chunk-XOR-swizzled: stored chunk c_st holds logical chunk c_st ^ (d&7).
__global__ void cvt_v(const float* __restrict__ vp, unsigned short* __restrict__ vtws) {
    const int bh = blockIdx.x >> 5;
    const int t  = blockIdx.x & 31;
    const int tid = threadIdx.x;
    __shared__ unsigned short ldsT[DIM][72];   // [d][local key]

    const int i = tid >> 2;
    const int dbase = (tid & 3) * 16;
    const float* src = vp + ((size_t)bh * S_LEN + t * 64 + i) * DIM + dbase;
#pragma unroll
    for (int q4 = 0; q4 < 4; ++q4) {
        const f32x4 a = *reinterpret_cast<const f32x4*>(src + q4 * 4);
#pragma unroll
        for (int j = 0; j < 4; ++j) ldsT[dbase + q4 * 4 + j][i] = f2bf(a[j]);
    }
    __syncthreads();
#pragma unroll
    for (int hh = 0; hh < 2; ++hh) {
        const int slot = tid + hh * 256;
        const int d = slot >> 3, c_st = slot & 7;
        const int cl = c_st ^ (d & 7);
        short8 t8;
#pragma unroll
        for (int j = 0; j < 8; ++j) {
            const int p = cl * 8 + j;
            const int kap = (p & 32) | ((p & 16) >> 1) | ((p & 8) >> 1) | ((p & 4) << 2) | (p & 3);
            t8[j] = (short)ldsT[d][kap];
        }
        unsigned short* dst = vtws + ((size_t)bh * DIM + d) * S_LEN + t * 64 + c_st * 8;
        *reinterpret_cast<short8*>(dst) = t8;
    }
}

// ---------------- main attention kernel (swapped-QK, fully lane-local P) ----------------
__global__ __launch_bounds__(256, 4)
void attn_fwd(const float* __restrict__ qp, const unsigned short* __restrict__ kws,
              const unsigned short* __restrict__ vtws, float* __restrict__ op) {
    const int lb = (blockIdx.x & 7) * 128 + (blockIdx.x >> 3);   // XCD swizzle (bijective)
    const int bh = lb >> 4;
    const int qb = lb & 15;
    const int tid  = threadIdx.x;
    const int wave = tid >> 6;
    const int lane = tid & 63;
    const int g = lane >> 4;
    const int r = lane & 15;

    __shared__ unsigned short klds[2][KVBLK * DIM];   // [key][chunk-swz] 8KB x2
    __shared__ unsigned short vlds[2][DIM * KVBLK];   // [d][pos-swz]     8KB x2

    const float*          qg    = qp   + (size_t)bh * (S_LEN * DIM);
    const unsigned short* kbase = kws  + (size_t)bh * (S_LEN * DIM);
    const unsigned short* vbase = vtws + (size_t)bh * (S_LEN * DIM);
    float*                og    = op   + (size_t)bh * (S_LEN * DIM);

    // Q frags (B-operand: col=q=lane&15, k=8g+i), pre-scaled by 0.125*log2(e) (base-2 scores)
    const float qscale = 0.125f * 1.44269504088896340736f;
    const int q0 = qb * QBLK + wave * 32;
    short8 qfrag[2][2];
#pragma unroll
    for (int mt = 0; mt < 2; ++mt) {
        const float* qrow = qg + (size_t)(q0 + mt * 16 + r) * DIM;
#pragma unroll
        for (int ks = 0; ks < 2; ++ks) {
            const f32x4 a = *reinterpret_cast<const f32x4*>(qrow + ks * 32 + 8 * g);
            const f32x4 b = *reinterpret_cast<const f32x4*>(qrow + ks * 32 + 8 * g + 4);
            short8 t;
            t[0] = (short)f2bf(a[0] * qscale); t[1] = (short)f2bf(a[1] * qscale);
            t[2] = (short)f2bf(a[2] * qscale); t[3] = (short)f2bf(a[3] * qscale);
            t[4] = (short)f2bf(b[0] * qscale); t[5] = (short)f2bf(b[1] * qscale);
            t[6] = (short)f2bf(b[2] * qscale); t[7] = (short)f2bf(b[3] * qscale);
            qfrag[mt][ks] = t;
        }
    }

    // O^T accumulators: o[mt][ntd][rg] = O^T[d=ntd*16+4g+rg][q=r]; lane-local m,l per mt
    f32x4 o[2][4];
    float m_run[2], l_part[2];
#pragma unroll
    for (int mt = 0; mt < 2; ++mt) {
#pragma unroll
        for (int nt = 0; nt < 4; ++nt) { f32x4 z = {0.f, 0.f, 0.f, 0.f}; o[mt][nt] = z; }
        m_run[mt] = -INFINITY; l_part[mt] = 0.0f;
    }

    const int srow = lane >> 3, schk = lane & 7;
    auto stage = [&](int t, int buf) {
        const int kv0 = t * KVBLK;
#pragma unroll
        for (int h = 0; h < 2; ++h) {
            const int row = wave * 16 + h * 8;
            gload16(kbase + (size_t)(kv0 + row + srow) * DIM + schk * 8,
                    &klds[buf][row * DIM]);
            gload16(vbase + (size_t)(row + srow) * S_LEN + kv0 + schk * 8,
                    &vlds[buf][row * DIM]);
        }
    };

    stage(0, 0);
    __syncthreads();
    int cur = 0;

    for (int t = 0; t < NKV; ++t) {
        if (t + 1 < NKV) stage(t + 1, cur ^ 1);   // prefetch; drains at end-of-iter barrier

        // ---- S^T = K Q^T : st[mt][nt][rg] = S[key=nt*16+4g+rg][q=r] (base-2 domain) ----
        f32x4 st[2][4];
#pragma unroll
        for (int nt = 0; nt < 4; ++nt) {
#pragma unroll
            for (int mt = 0; mt < 2; ++mt) { f32x4 z = {0.f,0.f,0.f,0.f}; st[mt][nt] = z; }
#pragma unroll
            for (int ks = 0; ks < 2; ++ks) {
                const short8 kf = *reinterpret_cast<const short8*>(
                    &klds[cur][(nt * 16 + r) * DIM + (((ks << 2) | g) ^ (r & 7)) * 8]);
#pragma unroll
                for (int mt = 0; mt < 2; ++mt)
                    st[mt][nt] = __builtin_amdgcn_mfma_f32_16x16x32_bf16(kf, qfrag[mt][ks], st[mt][nt], 0, 0, 0);
            }
        }

        // ---- in-register online softmax; P frags built lane-locally (phi mapping) ----
        short8 pfrag[2][2];
#pragma unroll
        for (int mt = 0; mt < 2; ++mt) {
            float mxn[4];
#pragma unroll
            for (int nt = 0; nt < 4; ++nt)
                mxn[nt] = fmaxf(fmaxf(st[mt][nt][0], st[mt][nt][1]),
                                fmaxf(st[mt][nt][2], st[mt][nt][3]));
            float mx = fmaxf(fmaxf(mxn[0], mxn[1]), fmaxf(mxn[2], mxn[3]));
            mx = fmaxf(mx, __shfl_xor(mx, 16));
            mx = fmaxf(mx, __shfl_xor(mx, 32));
            const float mnew = fmaxf(m_run[mt], mx);
            const float al = exp2f(m_run[mt] - mnew);    // exp2(-inf)=0 on first tile
            m_run[mt] = mnew;
#pragma unroll
            for (int nt = 0; nt < 4; ++nt) {
                f32x4 p = st[mt][nt];
                p[0] = exp2f(p[0] - mnew);
                p[1] = exp2f(p[1] - mnew);
                p[2] = exp2f(p[2] - mnew);
                p[3] = exp2f(p[3] - mnew);
                st[mt][nt] = p;
            }
            float sn[4];
#pragma unroll
            for (int nt = 0; nt < 4; ++nt)
                sn[nt] = (st[mt][nt][0] + st[mt][nt][1]) + (st[mt][nt][2] + st[mt][nt][3]);
            l_part[mt] = l_part[mt] * al + ((sn[0] + sn[1]) + (sn[2] + sn[3]));
#pragma unroll
            for (int nt = 0; nt < 4; ++nt) {
                f32x4 tt = o[mt][nt];
                tt[0] *= al; tt[1] *= al; tt[2] *= al; tt[3] *= al;
                o[mt][nt] = tt;
            }
            // pfrag[mt][ks] slot i = P[key = 32ks+16(i>>2)+4g+(i&3)] = st[mt][2ks+(i>>2)][i&3]
#pragma unroll
            for (int ks = 0; ks < 2; ++ks) {
                union { uint32_t u[4]; short8 v; } fr;
                asm("v_cvt_pk_bf16_f32 %0, %1, %2" : "=v"(fr.u[0])
                    : "v"(st[mt][2*ks][0]),   "v"(st[mt][2*ks][1]));
                asm("v_cvt_pk_bf16_f32 %0, %1, %2" : "=v"(fr.u[1])
                    : "v"(st[mt][2*ks][2]),   "v"(st[mt][2*ks][3]));
                asm("v_cvt_pk_bf16_f32 %0, %1, %2" : "=v"(fr.u[2])
                    : "v"(st[mt][2*ks+1][0]), "v"(st[mt][2*ks+1][1]));
                asm("v_cvt_pk_bf16_f32 %0, %1, %2" : "=v"(fr.u[3])
                    : "v"(st[mt][2*ks+1][2]), "v"(st[mt][2*ks+1][3]));
                pfrag[mt][ks] = fr.v;
            }
        }

        // ---- O^T += V^T P^T : A=V^T (kappa-permuted keys), B=P^T (same phi) ----
#pragma unroll
        for (int ntd = 0; ntd < 4; ++ntd) {
#pragma unroll
            for (int ks = 0; ks < 2; ++ks) {
                const short8 vf = *reinterpret_cast<const short8*>(
                    &vlds[cur][(ntd * 16 + r) * DIM + (((ks << 2) | g) ^ (r & 7)) * 8]);
#pragma unroll
                for (int mt = 0; mt < 2; ++mt)
                    o[mt][ntd] = __builtin_amdgcn_mfma_f32_16x16x32_bf16(vf, pfrag[mt][ks], o[mt][ntd], 0, 0, 0);
            }
        }

        __syncthreads();
        cur ^= 1;
    }

    // ---- epilogue: l reduce over the 4 lane-groups, O^T/l, float4 stores ----
#pragma unroll
    for (int mt = 0; mt < 2; ++mt) {
        float lfull = l_part[mt];
        lfull += __shfl_xor(lfull, 16);
        lfull += __shfl_xor(lfull, 32);
        const float inv = 1.0f / lfull;
        float* dst = og + (size_t)(q0 + mt * 16 + r) * DIM + 4 * g;
#pragma unroll
        for (int ntd = 0; ntd < 4; ++ntd) {
            f32x4 tt = o[mt][ntd];
            tt[0] *= inv; tt[1] *= inv; tt[2] *= inv; tt[3] *= inv;
            *reinterpret_cast<f32x4*>(dst + ntd * 16) = tt;
        }
    }
}

extern "C" void kernel_launch(void* const* d_in, const int* in_sizes, int n_in,
                              void* d_out, int out_size, void* d_ws, size_t ws_size,
                              hipStream_t stream) {
    const float* q = (const float*)d_in[0];
    const float* k = (const float*)d_in[1];
    const float* v = (const float*)d_in[2];
    float* out = (float*)d_out;
    unsigned short* kws  = (unsigned short*)d_ws;
    unsigned short* vtws = kws + (size_t)64 * S_LEN * DIM;
    cvt_k<<<dim3(64 * S_LEN * 8 / 256), 256, 0, stream>>>(k, kws);
    cvt_v<<<dim3(64 * (S_LEN / 64)), 256, 0, stream>>>(v, vtws);
    attn_fwd<<<dim3(1024), 256, 0, stream>>>(q, kws, vtws, out);
}

// Round 5
// 107.831 us; speedup vs baseline: 2.7834x; 1.3626x over previous
//
#include <hip/hip_runtime.h>
#include <stdint.h>
#include <math.h>

#define S_LEN 2048
#define DIM   64
#define QBLK  128
#define KVBLK 64
#define NKV   (S_LEN / KVBLK)   // 32

typedef __attribute__((ext_vector_type(8))) short short8;
typedef __attribute__((ext_vector_type(4))) float f32x4;

// fp32 -> bf16 round-to-nearest-even (cold paths only)
static __device__ __forceinline__ unsigned short f2bf(float f) {
    union { float f; uint32_t u; } cv; cv.f = f;
    uint32_t u = cv.u;
    return (unsigned short)((u + 0x7fffu + ((u >> 16) & 1u)) >> 16);
}

// async global->LDS, 16B per lane, LDS dest = wave-uniform base + lane*16
static __device__ __forceinline__ void gload16(const void* g, void* l) {
    __builtin_amdgcn_global_load_lds(
        (const __attribute__((address_space(1))) unsigned int*)g,
        (__attribute__((address_space(3))) unsigned int*)l, 16, 0, 0);
}

static __device__ __forceinline__ float vmax3(float a, float b, float c) {
    float d;
    asm("v_max3_f32 %0, %1, %2, %3" : "=v"(d) : "v"(a), "v"(b), "v"(c));
    return d;
}

// ---------------- pre-kernel 1: K fp32 -> bf16, per-row 16B-chunk XOR swizzle ----------------
__global__ void cvt_k(const float* __restrict__ kp, unsigned short* __restrict__ kws) {
    const int idx = blockIdx.x * 256 + threadIdx.x;
    const int c   = idx & 7;
    const int s   = (idx >> 3) & (S_LEN - 1);
    const int bh  = idx >> 14;
    const float* src = kp + ((size_t)bh * S_LEN + s) * DIM + c * 8;
    const f32x4 a = *reinterpret_cast<const f32x4*>(src);
    const f32x4 b = *reinterpret_cast<const f32x4*>(src + 4);
    short8 t;
    t[0] = (short)f2bf(a[0]); t[1] = (short)f2bf(a[1]);
    t[2] = (short)f2bf(a[2]); t[3] = (short)f2bf(a[3]);
    t[4] = (short)f2bf(b[0]); t[5] = (short)f2bf(b[1]);
    t[6] = (short)f2bf(b[2]); t[7] = (short)f2bf(b[3]);
    unsigned short* dst = kws + ((size_t)bh * S_LEN + s) * DIM + (size_t)((c ^ (s & 7)) * 8);
    *reinterpret_cast<short8*>(dst) = t;
}

// ---------------- pre-kernel 2: V fp32 -> bf16 transposed [d][key-position], kappa-permuted ----
// Position p holds key kappa(p) = 32*p5 + 8*p4 + 4*p3 + 16*p2 + 2*p1 + p0, so the PV B-frag
// (lane-local, phi-mapped P) and A-frag (V^T) agree on key order. Chunk-XOR-swizzled like K.
__global__ void cvt_v(const float* __restrict__ vp, unsigned short* __restrict__ vtws) {
    const int bh = blockIdx.x >> 5;
    const int t  = blockIdx.x & 31;
    const int tid = threadIdx.x;
    __shared__ unsigned short ldsT[DIM][72];   // [d][local key]

    const int i = tid >> 2;
    const int dbase = (tid & 3) * 16;
    const float* src = vp + ((size_t)bh * S_LEN + t * 64 + i) * DIM + dbase;
#pragma unroll
    for (int q4 = 0; q4 < 4; ++q4) {
        const f32x4 a = *reinterpret_cast<const f32x4*>(src + q4 * 4);
#pragma unroll
        for (int j = 0; j < 4; ++j) ldsT[dbase + q4 * 4 + j][i] = f2bf(a[j]);
    }
    __syncthreads();
#pragma unroll
    for (int hh = 0; hh < 2; ++hh) {
        const int slot = tid + hh * 256;
        const int d = slot >> 3, c_st = slot & 7;
        const int cl = c_st ^ (d & 7);
        short8 t8;
#pragma unroll
        for (int j = 0; j < 8; ++j) {
            const int p = cl * 8 + j;
            const int kap = (p & 32) | ((p & 16) >> 1) | ((p & 8) >> 1) | ((p & 4) << 2) | (p & 3);
            t8[j] = (short)ldsT[d][kap];
        }
        unsigned short* dst = vtws + ((size_t)bh * DIM + d) * S_LEN + t * 64 + c_st * 8;
        *reinterpret_cast<short8*>(dst) = t8;
    }
}

// ---------------- main attention kernel (swapped-QK, lane-local P, defer-max) ----------------
__global__ __launch_bounds__(256, 4)
void attn_fwd(const float* __restrict__ qp, const unsigned short* __restrict__ kws,
              const unsigned short* __restrict__ vtws, float* __restrict__ op) {
    const int lb = (blockIdx.x & 7) * 128 + (blockIdx.x >> 3);   // XCD swizzle (bijective)
    const int bh = lb >> 4;
    const int qb = lb & 15;
    const int tid  = threadIdx.x;
    const int wave = tid >> 6;
    const int lane = tid & 63;
    const int g = lane >> 4;
    const int r = lane & 15;

    __shared__ unsigned short klds[2][KVBLK * DIM];   // [key][chunk-swz] 8KB x2
    __shared__ unsigned short vlds[2][DIM * KVBLK];   // [d][pos-swz]     8KB x2

    const float*          qg    = qp   + (size_t)bh * (S_LEN * DIM);
    const unsigned short* kbase = kws  + (size_t)bh * (S_LEN * DIM);
    const unsigned short* vbase = vtws + (size_t)bh * (S_LEN * DIM);
    float*                og    = op   + (size_t)bh * (S_LEN * DIM);

    // Q frags (B-operand: col=q=lane&15, k=8g+i), pre-scaled by 0.125*log2(e) (base-2 scores)
    const float qscale = 0.125f * 1.44269504088896340736f;
    const int q0 = qb * QBLK + wave * 32;
    short8 qfrag[2][2];
#pragma unroll
    for (int mt = 0; mt < 2; ++mt) {
        const float* qrow = qg + (size_t)(q0 + mt * 16 + r) * DIM;
#pragma unroll
        for (int ks = 0; ks < 2; ++ks) {
            const f32x4 a = *reinterpret_cast<const f32x4*>(qrow + ks * 32 + 8 * g);
            const f32x4 b = *reinterpret_cast<const f32x4*>(qrow + ks * 32 + 8 * g + 4);
            short8 t;
            t[0] = (short)f2bf(a[0] * qscale); t[1] = (short)f2bf(a[1] * qscale);
            t[2] = (short)f2bf(a[2] * qscale); t[3] = (short)f2bf(a[3] * qscale);
            t[4] = (short)f2bf(b[0] * qscale); t[5] = (short)f2bf(b[1] * qscale);
            t[6] = (short)f2bf(b[2] * qscale); t[7] = (short)f2bf(b[3] * qscale);
            qfrag[mt][ks] = t;
        }
    }

    // O^T accumulators: o[mt][ntd][rg] = O^T[d=ntd*16+4g+rg][q=r]; lane-uniform m,l per mt
    f32x4 o[2][4];
    float m_run[2], l_part[2];
#pragma unroll
    for (int mt = 0; mt < 2; ++mt) {
#pragma unroll
        for (int nt = 0; nt < 4; ++nt) { f32x4 z = {0.f, 0.f, 0.f, 0.f}; o[mt][nt] = z; }
        m_run[mt] = -INFINITY; l_part[mt] = 0.0f;
    }

    const int srow = lane >> 3, schk = lane & 7;
    auto stage = [&](int t, int buf) {
        const int kv0 = t * KVBLK;
#pragma unroll
        for (int h = 0; h < 2; ++h) {
            const int row = wave * 16 + h * 8;
            gload16(kbase + (size_t)(kv0 + row + srow) * DIM + schk * 8,
                    &klds[buf][row * DIM]);
            gload16(vbase + (size_t)(row + srow) * S_LEN + kv0 + schk * 8,
                    &vlds[buf][row * DIM]);
        }
    };

    stage(0, 0);
    __syncthreads();
    int cur = 0;

    for (int t = 0; t < NKV; ++t) {
        if (t + 1 < NKV) stage(t + 1, cur ^ 1);   // prefetch; drains at end-of-iter barrier

        // ---- S^T = K Q^T : st[mt][nt][rg] = S[key=nt*16+4g+rg][q=r] (base-2 domain) ----
        f32x4 st[2][4];
#pragma unroll
        for (int nt = 0; nt < 4; ++nt) {
#pragma unroll
            for (int mt = 0; mt < 2; ++mt) { f32x4 z = {0.f,0.f,0.f,0.f}; st[mt][nt] = z; }
        }
        __builtin_amdgcn_s_setprio(1);
#pragma unroll
        for (int nt = 0; nt < 4; ++nt) {
#pragma unroll
            for (int ks = 0; ks < 2; ++ks) {
                const short8 kf = *reinterpret_cast<const short8*>(
                    &klds[cur][(nt * 16 + r) * DIM + (((ks << 2) | g) ^ (r & 7)) * 8]);
#pragma unroll
                for (int mt = 0; mt < 2; ++mt)
                    st[mt][nt] = __builtin_amdgcn_mfma_f32_16x16x32_bf16(kf, qfrag[mt][ks], st[mt][nt], 0, 0, 0);
            }
        }
        __builtin_amdgcn_s_setprio(0);

        // ---- in-register online softmax (defer-max, THR=8); lane-local P frags ----
        short8 pfrag[2][2];
#pragma unroll
        for (int mt = 0; mt < 2; ++mt) {
            // in-lane max of 16 scores: v_max3 tree, depth 3
            const f32x4 s0 = st[mt][0], s1 = st[mt][1], s2 = st[mt][2], s3 = st[mt][3];
            const float a0 = vmax3(s0[0], s0[1], s0[2]);
            const float a1 = vmax3(s0[3], s1[0], s1[1]);
            const float a2 = vmax3(s1[2], s1[3], s2[0]);
            const float a3 = vmax3(s2[1], s2[2], s2[3]);
            const float a4 = vmax3(s3[0], s3[1], s3[2]);
            const float lane_mx = fmaxf(vmax3(a0, a1, a2), vmax3(a3, a4, s3[3]));
            // defer-max: only rescale when some lane's max outgrew m_run by >8 (wave-uniform branch)
            if (__any(lane_mx > m_run[mt] + 8.0f)) {
                float mx = fmaxf(lane_mx, __shfl_xor(lane_mx, 16));
                mx = fmaxf(mx, __shfl_xor(mx, 32));
                const float mnew = fmaxf(m_run[mt], mx);
                const float al = __builtin_amdgcn_exp2f(m_run[mt] - mnew);  // -inf -> 0 on 1st tile
                m_run[mt] = mnew;
                l_part[mt] *= al;
#pragma unroll
                for (int nt = 0; nt < 4; ++nt) {
                    f32x4 tt = o[mt][nt];
                    tt[0] *= al; tt[1] *= al; tt[2] *= al; tt[3] *= al;
                    o[mt][nt] = tt;
                }
            }
            const float mnow = m_run[mt];
#pragma unroll
            for (int nt = 0; nt < 4; ++nt) {
                f32x4 p = st[mt][nt];
                p[0] = __builtin_amdgcn_exp2f(p[0] - mnow);
                p[1] = __builtin_amdgcn_exp2f(p[1] - mnow);
                p[2] = __builtin_amdgcn_exp2f(p[2] - mnow);
                p[3] = __builtin_amdgcn_exp2f(p[3] - mnow);
                st[mt][nt] = p;
            }
            float sn[4];
#pragma unroll
            for (int nt = 0; nt < 4; ++nt)
                sn[nt] = (st[mt][nt][0] + st[mt][nt][1]) + (st[mt][nt][2] + st[mt][nt][3]);
            l_part[mt] += (sn[0] + sn[1]) + (sn[2] + sn[3]);
            // pfrag[mt][ks] slot i = P[key = 32ks+16(i>>2)+4g+(i&3)] = st[mt][2ks+(i>>2)][i&3]
#pragma unroll
            for (int ks = 0; ks < 2; ++ks) {
                union { uint32_t u[4]; short8 v; } fr;
                asm("v_cvt_pk_bf16_f32 %0, %1, %2" : "=v"(fr.u[0])
                    : "v"(st[mt][2*ks][0]),   "v"(st[mt][2*ks][1]));
                asm("v_cvt_pk_bf16_f32 %0, %1, %2" : "=v"(fr.u[1])
                    : "v"(st[mt][2*ks][2]),   "v"(st[mt][2*ks][3]));
                asm("v_cvt_pk_bf16_f32 %0, %1, %2" : "=v"(fr.u[2])
                    : "v"(st[mt][2*ks+1][0]), "v"(st[mt][2*ks+1][1]));
                asm("v_cvt_pk_bf16_f32 %0, %1, %2" : "=v"(fr.u[3])
                    : "v"(st[mt][2*ks+1][2]), "v"(st[mt][2*ks+1][3]));
                pfrag[mt][ks] = fr.v;
            }
        }

        // ---- O^T += V^T P^T : A=V^T (kappa-permuted keys), B=P^T (same phi) ----
        __builtin_amdgcn_s_setprio(1);
#pragma unroll
        for (int ntd = 0; ntd < 4; ++ntd) {
#pragma unroll
            for (int ks = 0; ks < 2; ++ks) {
                const short8 vf = *reinterpret_cast<const short8*>(
                    &vlds[cur][(ntd * 16 + r) * DIM + (((ks << 2) | g) ^ (r & 7)) * 8]);
#pragma unroll
                for (int mt = 0; mt < 2; ++mt)
                    o[mt][ntd] = __builtin_amdgcn_mfma_f32_16x16x32_bf16(vf, pfrag[mt][ks], o[mt][ntd], 0, 0, 0);
            }
        }
        __builtin_amdgcn_s_setprio(0);

        __syncthreads();
        cur ^= 1;
    }

    // ---- epilogue: l reduce over the 4 lane-groups, O^T/l, float4 stores ----
#pragma unroll
    for (int mt = 0; mt < 2; ++mt) {
        float lfull = l_part[mt];
        lfull += __shfl_xor(lfull, 16);
        lfull += __shfl_xor(lfull, 32);
        const float inv = 1.0f / lfull;
        float* dst = og + (size_t)(q0 + mt * 16 + r) * DIM + 4 * g;
#pragma unroll
        for (int ntd = 0; ntd < 4; ++ntd) {
            f32x4 tt = o[mt][ntd];
            tt[0] *= inv; tt[1] *= inv; tt[2] *= inv; tt[3] *= inv;
            *reinterpret_cast<f32x4*>(dst + ntd * 16) = tt;
        }
    }
}

extern "C" void kernel_launch(void* const* d_in, const int* in_sizes, int n_in,
                              void* d_out, int out_size, void* d_ws, size_t ws_size,
                              hipStream_t stream) {
    const float* q = (const float*)d_in[0];
    const float* k = (const float*)d_in[1];
    const float* v = (const float*)d_in[2];
    float* out = (float*)d_out;
    unsigned short* kws  = (unsigned short*)d_ws;
    unsigned short* vtws = kws + (size_t)64 * S_LEN * DIM;
    cvt_k<<<dim3(64 * S_LEN * 8 / 256), 256, 0, stream>>>(k, kws);
    cvt_v<<<dim3(64 * (S_LEN / 64)), 256, 0, stream>>>(v, vtws);
    attn_fwd<<<dim3(1024), 256, 0, stream>>>(q, kws, vtws, out);
}